// Round 1
// baseline (640.010 us; speedup 1.0000x reference)
//
#include <hip/hip_runtime.h>
#include <hip/hip_bf16.h>

// INT8 dynamic-quant GEMM: out = (x_int8 @ w_int8^T) * (x_scales * w_scales^T)
// x: [M,K] f32, w: [N,K] f32, out: [M,N] f32.  M=8192, K=4096, N=11008.

#define QEPS 1e-5f

using int4v = __attribute__((ext_vector_type(4))) int;

typedef __attribute__((address_space(3))) signed char lds_i8_t;
typedef __attribute__((address_space(1))) const signed char glb_i8_t;

// ---------------- per-row absmax quantize (K = 4096 fixed) ----------------
// one block per row; 256 threads * 16 floats = 4096.
__global__ __launch_bounds__(256) void quant_rows_k(const float* __restrict__ in,
                                                    signed char* __restrict__ out8,
                                                    float* __restrict__ scales) {
    const int K = 4096;
    const int row = blockIdx.x;
    const int t = threadIdx.x;
    const float4* in4 = (const float4*)(in + (size_t)row * K);
    float4 v[4];
    float amax = 0.f;
#pragma unroll
    for (int j = 0; j < 4; ++j) {
        v[j] = in4[t + 256 * j];
        amax = fmaxf(amax, fmaxf(fmaxf(fabsf(v[j].x), fabsf(v[j].y)),
                                 fmaxf(fabsf(v[j].z), fabsf(v[j].w))));
    }
#pragma unroll
    for (int off = 32; off > 0; off >>= 1)
        amax = fmaxf(amax, __shfl_xor(amax, off));
    __shared__ float wmax[4];
    if ((t & 63) == 0) wmax[t >> 6] = amax;
    __syncthreads();
    amax = fmaxf(fmaxf(wmax[0], wmax[1]), fmaxf(wmax[2], wmax[3]));
    const float scale = fmaxf(amax, QEPS) / 127.0f;  // matches ref: max(amax,eps)/127
    if (t == 0) scales[row] = scale;
    char4* o4 = (char4*)(out8 + (size_t)row * K);
#pragma unroll
    for (int j = 0; j < 4; ++j) {
        char4 q;
        q.x = (signed char)(int)rintf(v[j].x / scale);  // rintf = round-half-even = jnp.round
        q.y = (signed char)(int)rintf(v[j].y / scale);
        q.z = (signed char)(int)rintf(v[j].z / scale);
        q.w = (signed char)(int)rintf(v[j].w / scale);
        o4[t + 256 * j] = q;
    }
}

// ---------------- int8 GEMM, 128x128 tile, BK=128, 4 waves ----------------
// A = x_int8 [M,K]; B = w_int8 [N,K] (row n = output col n); C [M,N] f32.
// LDS tiles stored with XOR swizzle: lds[row][x] = global[row][x ^ ((row&7)<<4)]
// (achieved by pre-swizzling the GLOBAL source addr; LDS dest stays linear,
//  as required by global_load_lds). Reads apply the same XOR.
__global__ __launch_bounds__(256) void gemm_i8_k(const signed char* __restrict__ A,
                                                 const signed char* __restrict__ B,
                                                 const float* __restrict__ xs,
                                                 const float* __restrict__ wsc,
                                                 float* __restrict__ C) {
    const int K = 4096;
    const int N = 11008;
    const int BK = 128;
    __shared__ __align__(16) signed char la[128 * 128];
    __shared__ __align__(16) signed char lb[128 * 128];

    const int t = threadIdx.x;
    const int lane = t & 63;
    const int wid = t >> 6;
    const int wr = wid >> 1;   // wave row (0..1) -> 64 rows each
    const int wc = wid & 1;    // wave col (0..1) -> 64 cols each
    const int brow = blockIdx.y * 128;
    const int bcol = blockIdx.x * 128;

    int4v acc[4][4];
#pragma unroll
    for (int m = 0; m < 4; ++m)
#pragma unroll
        for (int n = 0; n < 4; ++n) acc[m][n] = (int4v){0, 0, 0, 0};

    // staging geometry: chunk = j*256 + t (1024 chunks of 16B per tile)
    // row = chunk>>3 (= j*32 + (t>>3)), slot = chunk&7
    const int srow = t >> 3;
    const int scol = ((t & 7) * 16) ^ ((srow & 7) << 4);  // pre-swizzled source col
    const signed char* aptr = A + (size_t)(brow + srow) * K + scol;
    const signed char* bptr = B + (size_t)(bcol + srow) * K + scol;

    // fragment geometry (16x16x64 i8): A row = lane&15, k = (lane>>4)*16 + i
    const int arow0 = wr * 64 + (lane & 15);
    const int brow0 = wc * 64 + (lane & 15);
    const int kgrp = ((lane >> 4) & 3) * 16;
    const int sw = (lane & 7) << 4;  // (row&7)<<4 — row&7 == lane&7 for all frags

    for (int kt = 0; kt < K / BK; ++kt) {
#pragma unroll
        for (int j = 0; j < 4; ++j) {
            __builtin_amdgcn_global_load_lds((glb_i8_t*)(aptr + (size_t)j * 32 * K + kt * BK),
                                             (lds_i8_t*)(la + (j * 256 + t) * 16), 16, 0, 0);
            __builtin_amdgcn_global_load_lds((glb_i8_t*)(bptr + (size_t)j * 32 * K + kt * BK),
                                             (lds_i8_t*)(lb + (j * 256 + t) * 16), 16, 0, 0);
        }
        __syncthreads();
#pragma unroll
        for (int ks = 0; ks < 2; ++ks) {
            const int col = (ks * 64 + kgrp) ^ sw;
            int4v af[4], bf[4];
#pragma unroll
            for (int m = 0; m < 4; ++m)
                af[m] = *(const int4v*)(la + (arow0 + m * 16) * 128 + col);
#pragma unroll
            for (int n = 0; n < 4; ++n)
                bf[n] = *(const int4v*)(lb + (brow0 + n * 16) * 128 + col);
#pragma unroll
            for (int m = 0; m < 4; ++m)
#pragma unroll
                for (int n = 0; n < 4; ++n)
                    acc[m][n] = __builtin_amdgcn_mfma_i32_16x16x64_i8(af[m], bf[n], acc[m][n], 0, 0, 0);
        }
        __syncthreads();
    }

    // epilogue: C/D frag layout col=lane&15, row=(lane>>4)*4+reg  [m89]
    const int rgrp = ((lane >> 4) & 3) * 4;
    float wsv[4];
#pragma unroll
    for (int n = 0; n < 4; ++n) wsv[n] = wsc[bcol + wc * 64 + n * 16 + (lane & 15)];
#pragma unroll
    for (int m = 0; m < 4; ++m) {
#pragma unroll
        for (int r = 0; r < 4; ++r) {
            const int row = brow + wr * 64 + m * 16 + rgrp + r;
            const float xsv = xs[row];
            const size_t base = (size_t)row * N + bcol + wc * 64 + (lane & 15);
#pragma unroll
            for (int n = 0; n < 4; ++n)
                C[base + n * 16] = (float)acc[m][n][r] * (xsv * wsv[n]);
        }
    }
}

extern "C" void kernel_launch(void* const* d_in, const int* in_sizes, int n_in,
                              void* d_out, int out_size, void* d_ws, size_t ws_size,
                              hipStream_t stream) {
    const float* x = (const float*)d_in[0];
    const float* w = (const float*)d_in[1];
    float* out = (float*)d_out;

    const int K = 4096;
    const int M = in_sizes[0] / K;   // 8192
    const int N = in_sizes[1] / K;   // 11008

    // workspace layout
    signed char* x8 = (signed char*)d_ws;
    signed char* w8 = x8 + (size_t)M * K;
    float* xscales = (float*)(w8 + (size_t)N * K);
    float* wscales = xscales + M;

    quant_rows_k<<<M, 256, 0, stream>>>(x, x8, xscales);
    quant_rows_k<<<N, 256, 0, stream>>>(w, w8, wscales);
    gemm_i8_k<<<dim3(N / 128, M / 128), 256, 0, stream>>>(x8, w8, xscales, wscales, out);
}

// Round 2
// 480.513 us; speedup vs baseline: 1.3319x; 1.3319x over previous
//
#include <hip/hip_runtime.h>
#include <hip/hip_bf16.h>

// INT8 dynamic-quant GEMM: out = (x_int8 @ w_int8^T) * (x_scales * w_scales^T)
// x: [M,K] f32, w: [N,K] f32, out: [M,N] f32.  M=8192, K=4096, N=11008.

#define QEPS 1e-5f

using int4v = __attribute__((ext_vector_type(4))) int;

typedef __attribute__((address_space(3))) signed char lds_i8_t;
typedef __attribute__((address_space(1))) const signed char glb_i8_t;

// ---------------- per-row absmax quantize (K = 4096 fixed) ----------------
__global__ __launch_bounds__(256) void quant_rows_k(const float* __restrict__ in,
                                                    signed char* __restrict__ out8,
                                                    float* __restrict__ scales) {
    const int K = 4096;
    const int row = blockIdx.x;
    const int t = threadIdx.x;
    const float4* in4 = (const float4*)(in + (size_t)row * K);
    float4 v[4];
    float amax = 0.f;
#pragma unroll
    for (int j = 0; j < 4; ++j) {
        v[j] = in4[t + 256 * j];
        amax = fmaxf(amax, fmaxf(fmaxf(fabsf(v[j].x), fabsf(v[j].y)),
                                 fmaxf(fabsf(v[j].z), fabsf(v[j].w))));
    }
#pragma unroll
    for (int off = 32; off > 0; off >>= 1)
        amax = fmaxf(amax, __shfl_xor(amax, off));
    __shared__ float wmax[4];
    if ((t & 63) == 0) wmax[t >> 6] = amax;
    __syncthreads();
    amax = fmaxf(fmaxf(wmax[0], wmax[1]), fmaxf(wmax[2], wmax[3]));
    const float scale = fmaxf(amax, QEPS) / 127.0f;
    if (t == 0) scales[row] = scale;
    char4* o4 = (char4*)(out8 + (size_t)row * K);
#pragma unroll
    for (int j = 0; j < 4; ++j) {
        char4 q;
        q.x = (signed char)(int)rintf(v[j].x / scale);  // rintf = round-half-even = jnp.round
        q.y = (signed char)(int)rintf(v[j].y / scale);
        q.z = (signed char)(int)rintf(v[j].z / scale);
        q.w = (signed char)(int)rintf(v[j].w / scale);
        o4[t + 256 * j] = q;
    }
}

// ---------------- int8 GEMM, 256x256 tile, BK=128B, 8 waves, pipelined ----
// LDS tiles XOR-swizzled: lds[row][c] = global[row][c ^ ((row&7)<<4)]
// (pre-swizzled GLOBAL source addr; LDS dest linear, as global_load_lds needs).
// 2-deep double buffer; counted vmcnt(8) — loads stay in flight across the
// barrier (T4); setprio around MFMA clusters (T5); XCD block swizzle (T1).
__global__ __launch_bounds__(512, 2) void gemm_i8_256(const signed char* __restrict__ A,
                                                      const signed char* __restrict__ B,
                                                      const float* __restrict__ xs,
                                                      const float* __restrict__ wsc,
                                                      float* __restrict__ C) {
    constexpr int K = 4096;
    constexpr int N = 11008;
    constexpr int BK = 128;
    constexpr int NT = K / BK;      // 32
    constexpr int TILE = 256 * 128; // 32 KB

    __shared__ __align__(16) signed char lds[4 * TILE];  // 128 KB
    signed char* const la0 = lds;
    signed char* const la1 = lds + TILE;
    signed char* const lb0 = lds + 2 * TILE;
    signed char* const lb1 = lds + 3 * TILE;

    const int t = threadIdx.x;
    const int lane = t & 63;
    const int wid = t >> 6;
    const int wr = wid >> 2;   // 0..1 -> 128 rows each
    const int wc = wid & 3;    // 0..3 -> 64 cols each

    // XCD-aware swizzle: grid 1376 = 8 XCDs x 172 (bijective)
    const int wg = (blockIdx.x & 7) * ((int)gridDim.x >> 3) + ((int)blockIdx.x >> 3);
    const int by = wg / 43;
    const int bx = wg - by * 43;
    const int brow = by * 256;
    const int bcol = bx * 256;

    // staging: chunk = j*512+t; row = chunk>>3 (0..255), slot = chunk&7
    const int srow = t >> 3;                               // 0..63, +64 per j
    const int scol = ((t & 7) * 16) ^ ((srow & 7) << 4);   // pre-swizzled source col
    const signed char* aptr = A + (size_t)(brow + srow) * K + scol;
    const signed char* bptr = B + (size_t)(bcol + srow) * K + scol;

    // fragment geometry (mfma_i32_16x16x64_i8): row = lane&15, k-slot = (lane>>4)*16
    const int arow0 = wr * 128 + (lane & 15);
    const int bcol0 = wc * 64 + (lane & 15);
    const int kgrp = (lane >> 4) * 16;
    const int sw = (lane & 7) << 4;   // row&7 == lane&7 for all fragment rows

    int4v acc[8][4];
#pragma unroll
    for (int m = 0; m < 8; ++m)
#pragma unroll
        for (int n = 0; n < 4; ++n) acc[m][n] = (int4v){0, 0, 0, 0};

#define STAGE(LA, LB, KT)                                                                  \
    do {                                                                                   \
        _Pragma("unroll") for (int j = 0; j < 4; ++j)                                      \
            __builtin_amdgcn_global_load_lds(                                              \
                (glb_i8_t*)(aptr + (size_t)(j * 64) * K + (size_t)(KT)*BK),                \
                (lds_i8_t*)((LA) + (j * 512 + t) * 16), 16, 0, 0);                         \
        _Pragma("unroll") for (int j = 0; j < 4; ++j)                                      \
            __builtin_amdgcn_global_load_lds(                                              \
                (glb_i8_t*)(bptr + (size_t)(j * 64) * K + (size_t)(KT)*BK),                \
                (lds_i8_t*)((LB) + (j * 512 + t) * 16), 16, 0, 0);                         \
    } while (0)

    auto compute_tile = [&](const signed char* LA, const signed char* LB) {
#pragma unroll
        for (int ks = 0; ks < 2; ++ks) {
            int4v bf[4];
#pragma unroll
            for (int n = 0; n < 4; ++n)
                bf[n] = *(const int4v*)(LB + (bcol0 + n * 16) * 128 + ((ks * 64 + kgrp) ^ sw));
#pragma unroll
            for (int mh = 0; mh < 2; ++mh) {
                int4v af[4];
#pragma unroll
                for (int mi = 0; mi < 4; ++mi)
                    af[mi] = *(const int4v*)(LA + (arow0 + (mh * 4 + mi) * 16) * 128 +
                                             ((ks * 64 + kgrp) ^ sw));
                __builtin_amdgcn_s_setprio(1);
#pragma unroll
                for (int mi = 0; mi < 4; ++mi)
#pragma unroll
                    for (int n = 0; n < 4; ++n)
                        acc[mh * 4 + mi][n] = __builtin_amdgcn_mfma_i32_16x16x64_i8(
                            af[mi], bf[n], acc[mh * 4 + mi][n], 0, 0, 0);
                __builtin_amdgcn_s_setprio(0);
            }
        }
    };

    // prologue: stage tiles 0 and 1; wait only for tile 0 (vmcnt(8))
    STAGE(la0, lb0, 0);
    STAGE(la1, lb1, 1);
    asm volatile("s_waitcnt vmcnt(8)" ::: "memory");
    __builtin_amdgcn_s_barrier();

#pragma unroll 1
    for (int kt = 0; kt < NT; kt += 2) {
        compute_tile(la0, lb0);
        __builtin_amdgcn_s_barrier();            // all waves done reading buf0
        STAGE(la0, lb0, (kt + 2) & (NT - 1));    // wrapped tail stages are redundant-but-safe
        asm volatile("s_waitcnt vmcnt(8)" ::: "memory");  // tile kt+1 landed; kt+2 in flight
        __builtin_amdgcn_s_barrier();
        compute_tile(la1, lb1);
        __builtin_amdgcn_s_barrier();
        STAGE(la1, lb1, (kt + 3) & (NT - 1));
        asm volatile("s_waitcnt vmcnt(8)" ::: "memory");
        __builtin_amdgcn_s_barrier();
    }
#undef STAGE

    // epilogue: C/D frag layout col=lane&15, row=(lane>>4)*4+reg
    const int rgrp = (lane >> 4) * 4;
    float wsv[4];
#pragma unroll
    for (int n = 0; n < 4; ++n) wsv[n] = wsc[bcol + wc * 64 + n * 16 + (lane & 15)];
#pragma unroll
    for (int m = 0; m < 8; ++m) {
#pragma unroll
        for (int r = 0; r < 4; ++r) {
            const int row = brow + wr * 128 + m * 16 + rgrp + r;
            const float xsv = xs[row];
            const size_t base = (size_t)row * N + bcol + wc * 64 + (lane & 15);
#pragma unroll
            for (int n = 0; n < 4; ++n)
                C[base + n * 16] = (float)acc[m][n][r] * (xsv * wsv[n]);
        }
    }
}

extern "C" void kernel_launch(void* const* d_in, const int* in_sizes, int n_in,
                              void* d_out, int out_size, void* d_ws, size_t ws_size,
                              hipStream_t stream) {
    const float* x = (const float*)d_in[0];
    const float* w = (const float*)d_in[1];
    float* out = (float*)d_out;

    const int K = 4096;
    const int M = in_sizes[0] / K;   // 8192
    const int N = in_sizes[1] / K;   // 11008

    signed char* x8 = (signed char*)d_ws;
    signed char* w8 = x8 + (size_t)M * K;
    float* xscales = (float*)(w8 + (size_t)N * K);
    float* wscales = xscales + M;

    quant_rows_k<<<M, 256, 0, stream>>>(x, x8, xscales);
    quant_rows_k<<<N, 256, 0, stream>>>(w, w8, wscales);
    const int nwg = (M / 256) * (N / 256);   // 32*43 = 1376 = 8*172
    gemm_i8_256<<<nwg, 512, 0, stream>>>(x8, w8, xscales, wscales, out);
}